// Round 2
// baseline (985.823 us; speedup 1.0000x reference)
//
#include <hip/hip_runtime.h>
#include <hip/hip_bf16.h>

#define B 32
#define N 4096
#define C 768
#define H 12
#define HD 64
// SCALE = 1/sqrt(64) = 0.125f

// K1: q[b,co] = sum_c x[b,0,c] * Wq[c,co]
__global__ __launch_bounds__(256) void k1_q(const float* __restrict__ x,
                                            const float* __restrict__ Wq,
                                            float* __restrict__ q) {
    __shared__ float xs[C];
    int b = blockIdx.x / 3;
    int coBase = (blockIdx.x % 3) * 256;
    int t = threadIdx.x;
    for (int i = t; i < C; i += 256) xs[i] = x[(size_t)b * N * C + i];
    __syncthreads();
    int co = coBase + t;
    float acc = 0.f;
    for (int c = 0; c < C; ++c) acc = fmaf(xs[c], Wq[(size_t)c * C + co], acc);
    q[b * C + co] = acc;
}

// K2: qk[b,h,c] = SCALE * sum_d q[b,h*64+d] * Wk[c, h*64+d]; also zero xa
__global__ __launch_bounds__(256) void k2_qk(const float* __restrict__ q,
                                             const float* __restrict__ Wk,
                                             float* __restrict__ qk,
                                             float* __restrict__ xa) {
    int id = blockIdx.x * 256 + threadIdx.x;   // 294912 = B*H*C
    xa[id] = 0.f;
    int b = id / (H * C);
    int r = id % (H * C);
    int h = r / C;
    int c = r % C;
    const float* wrow = Wk + (size_t)c * C + h * HD;
    const float* qrow = q + b * C + h * HD;
    float acc = 0.f;
#pragma unroll
    for (int j = 0; j < HD / 4; ++j) {
        float4 wv = *(const float4*)(wrow + j * 4);
        float4 qv = *(const float4*)(qrow + j * 4);
        acc += wv.x * qv.x + wv.y * qv.y + wv.z * qv.z + wv.w * qv.w;
    }
    qk[id] = acc * 0.125f;
}

// K3: p[b,n,h] = x[b,n,:] . qk[b,h,:]   (pre-softmax scores, SCALE folded in)
__global__ __launch_bounds__(256) void k3_scores(const float* __restrict__ x,
                                                 const float* __restrict__ qk,
                                                 float* __restrict__ p) {
    __shared__ float4 qks[H * C / 4];   // 36 KB
    int b = blockIdx.x >> 5;            // 32 n-chunks of 128 rows
    int chunk = blockIdx.x & 31;
    int t = threadIdx.x;
    const float4* qg = (const float4*)(qk + (size_t)b * H * C);
    for (int i = t; i < H * C / 4; i += 256) qks[i] = qg[i];
    __syncthreads();
    int wave = t >> 6, lane = t & 63;
    for (int rr = 0; rr < 32; ++rr) {
        int n = chunk * 128 + wave * 32 + rr;
        const float4* xr = (const float4*)(x + ((size_t)b * N + n) * C);
        float4 X0 = xr[lane];
        float4 X1 = xr[64 + lane];
        float4 X2 = xr[128 + lane];
        float partial[H];
#pragma unroll
        for (int h = 0; h < H; ++h) {
            float4 a0 = qks[h * 192 + lane];
            float4 a1 = qks[h * 192 + 64 + lane];
            float4 a2 = qks[h * 192 + 128 + lane];
            float s = X0.x * a0.x;
            s = fmaf(X0.y, a0.y, s); s = fmaf(X0.z, a0.z, s); s = fmaf(X0.w, a0.w, s);
            s = fmaf(X1.x, a1.x, s); s = fmaf(X1.y, a1.y, s);
            s = fmaf(X1.z, a1.z, s); s = fmaf(X1.w, a1.w, s);
            s = fmaf(X2.x, a2.x, s); s = fmaf(X2.y, a2.y, s);
            s = fmaf(X2.z, a2.z, s); s = fmaf(X2.w, a2.w, s);
            partial[h] = s;
        }
#pragma unroll
        for (int h = 0; h < H; ++h) {
            float v = partial[h];
            for (int off = 32; off > 0; off >>= 1) v += __shfl_xor(v, off);
            partial[h] = v;
        }
        float ov = 0.f;
#pragma unroll
        for (int h = 0; h < H; ++h)
            if (lane == h) ov = partial[h];
        if (lane < H) p[((size_t)b * N + n) * H + lane] = ov;
    }
}

// K4: softmax over n for each (b,h); in place on p[B,N,H]
__global__ __launch_bounds__(256) void k4_softmax(float* __restrict__ p) {
    int b = blockIdx.x / H, h = blockIdx.x % H;
    float* pr = p + (size_t)b * N * H + h;
    int t = threadIdx.x;
    float vals[16];
    float m = -1e30f;
#pragma unroll
    for (int i = 0; i < 16; ++i) {
        vals[i] = pr[(size_t)(t + i * 256) * H];
        m = fmaxf(m, vals[i]);
    }
    __shared__ float red[4];
    __shared__ float red2[4];
    for (int off = 32; off > 0; off >>= 1) m = fmaxf(m, __shfl_xor(m, off));
    if ((t & 63) == 0) red[t >> 6] = m;
    __syncthreads();
    m = fmaxf(fmaxf(red[0], red[1]), fmaxf(red[2], red[3]));
    float s = 0.f;
#pragma unroll
    for (int i = 0; i < 16; ++i) {
        vals[i] = __expf(vals[i] - m);
        s += vals[i];
    }
    for (int off = 32; off > 0; off >>= 1) s += __shfl_xor(s, off);
    if ((t & 63) == 0) red2[t >> 6] = s;
    __syncthreads();
    s = red2[0] + red2[1] + red2[2] + red2[3];
    float inv = 1.f / s;
#pragma unroll
    for (int i = 0; i < 16; ++i) pr[(size_t)(t + i * 256) * H] = vals[i] * inv;
}

// K5: xa[b,h,c] += sum_n p[b,n,h] * x[b,n,c]   (partials over 4 n-splits, atomic combine)
__global__ __launch_bounds__(256) void k5_xa(const float* __restrict__ x,
                                             const float* __restrict__ p,
                                             float* __restrict__ xa) {
    int gid = blockIdx.x;            // 32 b * 6 c-chunks * 4 n-splits = 768
    int b = gid / 24;
    int rem = gid % 24;
    int cc = rem / 4;
    int ns = rem % 4;
    int t = threadIdx.x;
    int g = t >> 6;                  // 4 wave-groups, 3 heads each
    int c = cc * 128 + (t & 63) * 2;
    float2 a0 = {0.f, 0.f}, a1 = {0.f, 0.f}, a2 = {0.f, 0.f};
    int n0 = ns * 1024;
    for (int n = n0; n < n0 + 1024; ++n) {
        const float2 xv = *(const float2*)(x + ((size_t)b * N + n) * C + c);
        const float* pr = p + ((size_t)b * N + n) * H + g * 3;
        float p0 = pr[0], p1 = pr[1], p2 = pr[2];
        a0.x = fmaf(p0, xv.x, a0.x); a0.y = fmaf(p0, xv.y, a0.y);
        a1.x = fmaf(p1, xv.x, a1.x); a1.y = fmaf(p1, xv.y, a1.y);
        a2.x = fmaf(p2, xv.x, a2.x); a2.y = fmaf(p2, xv.y, a2.y);
    }
    int h0 = g * 3;
    atomicAdd(&xa[((size_t)b * H + h0    ) * C + c    ], a0.x);
    atomicAdd(&xa[((size_t)b * H + h0    ) * C + c + 1], a0.y);
    atomicAdd(&xa[((size_t)b * H + h0 + 1) * C + c    ], a1.x);
    atomicAdd(&xa[((size_t)b * H + h0 + 1) * C + c + 1], a1.y);
    atomicAdd(&xa[((size_t)b * H + h0 + 2) * C + c    ], a2.x);
    atomicAdd(&xa[((size_t)b * H + h0 + 2) * C + c + 1], a2.y);
}

// K6: o[b, h*64+d] = sum_c xa[b,h,c] * Wv[c, h*64+d]
__global__ __launch_bounds__(256) void k6_o(const float* __restrict__ xa,
                                            const float* __restrict__ Wv,
                                            float* __restrict__ o) {
    int id = blockIdx.x * 256 + threadIdx.x;   // B*C
    int b = id / C;
    int r = id % C;
    int h = r / HD;
    const float* xr = xa + ((size_t)b * H + h) * C;
    const float* wcol = Wv + r;   // Wv[c, r] column; note r = h*64+d
    float acc = 0.f;
    for (int c = 0; c < C; ++c) acc = fmaf(xr[c], wcol[(size_t)c * C], acc);
    o[id] = acc;
}

// K7: out[b,co] = bp[co] + sum_c o[b,c] * Wp[c,co]
__global__ __launch_bounds__(256) void k7_out(const float* __restrict__ o,
                                              const float* __restrict__ Wp,
                                              const float* __restrict__ bp,
                                              float* __restrict__ out) {
    int id = blockIdx.x * 256 + threadIdx.x;
    int b = id / C;
    int co = id % C;
    const float* orow = o + (size_t)b * C;
    float acc = bp[co];
    for (int c = 0; c < C; ++c) acc = fmaf(orow[c], Wp[(size_t)c * C + co], acc);
    out[id] = acc;
}

extern "C" void kernel_launch(void* const* d_in, const int* in_sizes, int n_in,
                              void* d_out, int out_size, void* d_ws, size_t ws_size,
                              hipStream_t stream) {
    const float* x  = (const float*)d_in[0];
    const float* Wq = (const float*)d_in[1];
    const float* Wk = (const float*)d_in[2];
    const float* Wv = (const float*)d_in[3];
    const float* Wp = (const float*)d_in[4];
    const float* bp = (const float*)d_in[5];
    float* out = (float*)d_out;

    float* ws = (float*)d_ws;
    float* q  = ws;                         // B*C       = 24576
    float* qk = q + B * C;                  // B*H*C     = 294912
    float* p  = qk + (size_t)B * H * C;     // B*N*H     = 1572864
    float* xa = p + (size_t)B * N * H;      // B*H*C     = 294912
    float* o  = xa + (size_t)B * H * C;     // B*C       = 24576

    k1_q      <<<96,   256, 0, stream>>>(x, Wq, q);
    k2_qk     <<<1152, 256, 0, stream>>>(q, Wk, qk, xa);
    k3_scores <<<1024, 256, 0, stream>>>(x, qk, p);
    k4_softmax<<<384,  256, 0, stream>>>(p);
    k5_xa     <<<768,  256, 0, stream>>>(x, p, xa);
    k6_o      <<<96,   256, 0, stream>>>(xa, Wv, o);
    k7_out    <<<96,   256, 0, stream>>>(o, Wp, bp, out);
}